// Round 2
// baseline (321.430 us; speedup 1.0000x reference)
//
#include <hip/hip_runtime.h>

// SelfAttention2d: B=4, C=128, EMB=16, N=64*64=4096.
// Strategy: fp32 projections -> split-bf16 (hi+lo) Q/K/V in ws ->
// MFMA flash attention with exact (hi+lo)x(hi+lo) products via the
// K=32 pack trick on mfma_f32_16x16x32_bf16. ~fp32 precision throughout.

#define SHIFT 16.0f
#define NT 128            // 4096 / 32 keys per tile

typedef __attribute__((ext_vector_type(8))) short bf16x8;
typedef __attribute__((ext_vector_type(4))) float f32x4;

__device__ __forceinline__ short f2bf(float f) {
  unsigned u = __float_as_uint(f);
  unsigned r = (u + 0x7FFFu + ((u >> 16) & 1u)) >> 16;  // RNE
  return (short)r;
}
__device__ __forceinline__ float bf2f(short s) {
  return __uint_as_float(((unsigned)(unsigned short)s) << 16);
}
__device__ __forceinline__ void async16(const void* g, void* l) {
  __builtin_amdgcn_global_load_lds(
      (const __attribute__((address_space(1))) void*)g,
      (__attribute__((address_space(3))) void*)l, 16, 0, 0);
}

// ---------------------------------------------------------------------------
// Projection kernel: q = Wq x + bq, k = Wk x + bk, v = Wv x + bv  (fp32),
// stored as split bf16:
//   Qg[b][n][32]: slots 0..15 = bf16_hi(q[e]), 16..31 = bf16_lo residual
//   Kg[b][m][32]: same packing
//   Vg[b][ch][d][32]: ch = m>>4; slots 0..15 = vh[d][m], 16..31 = vl
// 256 blocks (b, 64-pixel tile), 256 threads.
// ---------------------------------------------------------------------------
__global__ __launch_bounds__(256, 1) void proj_kernel(
    const float* __restrict__ xg, const float* __restrict__ Wq,
    const float* __restrict__ bq, const float* __restrict__ Wk,
    const float* __restrict__ bk, const float* __restrict__ Wv,
    const float* __restrict__ bv,
    short* __restrict__ Qg, short* __restrict__ Kg, short* __restrict__ Vg) {
  __shared__ float x_lds[64][132];  // [pixel][channel], +4 pad (16B-aligned rows)
  const int bid = blockIdx.x;
  const int b = bid >> 6;
  const int n0 = (bid & 63) << 6;
  const int tid = threadIdx.x;

  // stage x tile: x[b][c][n0..n0+63] -> x_lds[p][c]
  for (int idx = tid; idx < 2048; idx += 256) {
    int cc = idx >> 4;
    int p4 = (idx & 15) << 2;
    f32x4 xv = *(const f32x4*)(xg + ((size_t)(b * 128 + cc)) * 4096 + n0 + p4);
#pragma unroll
    for (int j2 = 0; j2 < 4; j2++) x_lds[p4 + j2][cc] = xv[j2];
  }
  __syncthreads();

  const int tx = tid & 15;   // output-group: d in {tx+16*di}, e = tx
  const int ty = tid >> 4;   // pixel group: p = ty*4 + pi

  float accv[4][8];
  float accq[4][2];
#pragma unroll
  for (int pi = 0; pi < 4; pi++) {
#pragma unroll
    for (int di = 0; di < 8; di++) accv[pi][di] = 0.f;
    accq[pi][0] = 0.f;
    accq[pi][1] = 0.f;
  }

  for (int c0 = 0; c0 < 128; c0 += 4) {
    f32x4 xv[4];
#pragma unroll
    for (int pi = 0; pi < 4; pi++) xv[pi] = *(const f32x4*)&x_lds[ty * 4 + pi][c0];
#pragma unroll
    for (int di = 0; di < 8; di++) {
      f32x4 wv = *(const f32x4*)(Wv + (size_t)(tx + 16 * di) * 128 + c0);
#pragma unroll
      for (int pi = 0; pi < 4; pi++)
        accv[pi][di] += xv[pi][0] * wv[0] + xv[pi][1] * wv[1] +
                        xv[pi][2] * wv[2] + xv[pi][3] * wv[3];
    }
    {
      f32x4 wq = *(const f32x4*)(Wq + (size_t)tx * 128 + c0);
      f32x4 wk = *(const f32x4*)(Wk + (size_t)tx * 128 + c0);
#pragma unroll
      for (int pi = 0; pi < 4; pi++) {
        accq[pi][0] += xv[pi][0] * wq[0] + xv[pi][1] * wq[1] +
                       xv[pi][2] * wq[2] + xv[pi][3] * wq[3];
        accq[pi][1] += xv[pi][0] * wk[0] + xv[pi][1] * wk[1] +
                       xv[pi][2] * wk[2] + xv[pi][3] * wk[3];
      }
    }
  }

  const float bqv = bq[tx], bkv = bk[tx];
#pragma unroll
  for (int pi = 0; pi < 4; pi++) {
    const int n = n0 + ty * 4 + pi;
    const size_t qk_base = ((size_t)b * 4096 + n) * 32;
    float qv = accq[pi][0] + bqv;
    short h = f2bf(qv);
    Qg[qk_base + tx] = h;
    Qg[qk_base + tx + 16] = f2bf(qv - bf2f(h));
    float kv = accq[pi][1] + bkv;
    h = f2bf(kv);
    Kg[qk_base + tx] = h;
    Kg[qk_base + tx + 16] = f2bf(kv - bf2f(h));
    const int ch = n >> 4, tt = n & 15;
#pragma unroll
    for (int di = 0; di < 8; di++) {
      const int d = tx + 16 * di;
      float vv = accv[pi][di] + bv[d];
      size_t vb = (((size_t)b * 256 + ch) * 128 + d) * 32 + tt;
      short vh = f2bf(vv);
      Vg[vb] = vh;
      Vg[vb + 16] = f2bf(vv - bf2f(vh));
    }
  }
}

// ---------------------------------------------------------------------------
// Flash kernel. 256 blocks (1/CU), 512 threads (8 waves).
// Block = (batch b, 64 queries). Tiles of TM=32 keys, 128 iterations.
// Wave w: npos = w>>1 (16 query rows), wpar = w&1.
//   S phase : wave computes 16x16 S-tile (npos, chunk=wpar) with 2 MFMAs
//             (pack A=[qh|ql]; B=[kh|kl] then [kl|kh] -> exact (q)(k)),
//             exp (fp32, fixed SHIFT), split p -> P_lds, row-sums kept in
//             per-lane registers (no atomics in the hot loop).
//   PV phase: wave computes 4 out-tiles (npos, dpos=wpar*4+j), 2 chunks x
//             2 MFMAs each (A=[ph|pl]; B=[vh|vl],[vl|vh] -> exact (p)(v)).
// K/V double-buffered via global_load_lds(16B); stage issue sits between the
// two barriers so the loads overlap the PV phase (no vmcnt(0) drain mid-loop
// with outstanding loads).
// LDS: K 2*2048 | V 2*16384 | P 64 rows * 72 bf16 (pad 8) = 46080 B static.
// ---------------------------------------------------------------------------
#define KO 0
#define VO 4096
#define PO 36864
#define SMEM_SZ 46080

__global__ __launch_bounds__(512, 2) void flash_kernel(
    const short* __restrict__ Qg, const short* __restrict__ Kg,
    const short* __restrict__ Vg, const float* __restrict__ xg,
    const float* __restrict__ gammag, float* __restrict__ outg) {
  __shared__ __align__(16) char smem[SMEM_SZ];
  __shared__ float Lpart[2][64];

  // XCD-aware swizzle: batch b lives on XCDs {2b, 2b+1}; its 2.25MB K/V set
  // fits a 4MB XCD L2.
  const int bid = blockIdx.x;
  const int xcd = bid & 7, slot = bid >> 3;
  const int b = xcd >> 1;
  const int nt = (slot << 1) | (xcd & 1);
  const int n0 = nt << 6;

  const int tid = threadIdx.x;
  const int l = tid & 63, w = tid >> 6;
  const int c = l & 15, g = l >> 4;
  const int npos = w >> 1, wpar = w & 1;

  const char* kg_b = (const char*)Kg + (size_t)b * 262144;   // 4096*64B
  const char* vg_b = (const char*)Vg + (size_t)b * 2097152;  // 256*128*32*2B

  // stage tile 0 into buffer 0 (K: 128 issues, V: 1024 issues, 16B each)
  {
#pragma unroll
    for (int kk = 0; kk < 3; kk++) {
      int idx = tid + kk * 512;
      if (idx < 128)
        async16(kg_b + idx * 16, smem + KO + idx * 16);
      else if (idx < 1152) {
        int v = idx - 128;
        async16(vg_b + v * 16, smem + VO + v * 16);
      }
    }
  }

  // Q fragment: lane holds row (npos*16+c), kslots 8g..8g+7 of [qh|ql]
  const bf16x8 qfrag =
      *(const bf16x8*)(Qg + ((size_t)b * 4096 + n0 + npos * 16 + c) * 32 + g * 8);

  f32x4 zero4 = {0.f, 0.f, 0.f, 0.f};
  f32x4 acc[4];
#pragma unroll
  for (int j = 0; j < 4; j++) acc[j] = zero4;
  float lsum[4] = {0.f, 0.f, 0.f, 0.f};

  asm volatile("s_waitcnt vmcnt(0)" ::: "memory");
  __syncthreads();

  for (int t = 0; t < NT; t++) {
    const int cur = t & 1;

    // ---- S phase: S = (qh+ql).(kh+kl) exactly, 2 MFMAs ----
    const char* kbase = smem + KO + cur * 2048;
    const int mrow = wpar * 16 + c;
    bf16x8 kb1 = *(const bf16x8*)(kbase + mrow * 64 + g * 16);
    bf16x8 kb2 = *(const bf16x8*)(kbase + mrow * 64 + (g ^ 2) * 16);
    f32x4 s = __builtin_amdgcn_mfma_f32_16x16x32_bf16(qfrag, kb1, zero4, 0, 0, 0);
    s = __builtin_amdgcn_mfma_f32_16x16x32_bf16(qfrag, kb2, s, 0, 0, 0);

    short* prow_base = (short*)(smem + PO);
#pragma unroll
    for (int i = 0; i < 4; i++) {
      float p = __expf(s[i] - SHIFT);  // no per-row max needed: |S| << 88
      float r = p;
      r += __shfl_xor(r, 1);
      r += __shfl_xor(r, 2);
      r += __shfl_xor(r, 4);
      r += __shfl_xor(r, 8);  // row-sum over the 16 column lanes
      lsum[i] += r;           // register accumulate; no LDS atomics
      short ph = f2bf(p);
      short pl = f2bf(p - bf2f(ph));
      const int n = npos * 16 + 4 * g + i;  // C/D: row = 4*(l>>4)+reg
      short* pr = prow_base + n * 72 + wpar * 32;
      pr[c] = ph;       // kslots 0..15 : p_hi
      pr[c + 16] = pl;  // kslots 16..31: p_lo
    }

    __syncthreads();  // P visible; no outstanding vmem here -> cheap barrier

    // issue next tile's staging now so it overlaps the PV phase
    if (t + 1 < NT) {
      const char* kg_t = kg_b + (size_t)(t + 1) * 2048;
      const char* vg_t = vg_b + (size_t)(t + 1) * 16384;
      char* kl = smem + KO + (cur ^ 1) * 2048;
      char* vl = smem + VO + (cur ^ 1) * 16384;
#pragma unroll
      for (int kk = 0; kk < 3; kk++) {
        int idx = tid + kk * 512;
        if (idx < 128)
          async16(kg_t + idx * 16, kl + idx * 16);
        else if (idx < 1152) {
          int v = idx - 128;
          async16(vg_t + v * 16, vl + v * 16);
        }
      }
    }

    // ---- PV phase: out += (ph+pl).(vh+vl) exactly, 2 MFMAs per chunk ----
    const char* vbase = smem + VO + cur * 16384;
    const short* Pp = (const short*)(smem + PO);
#pragma unroll
    for (int ch = 0; ch < 2; ch++) {
      bf16x8 af = *(const bf16x8*)(Pp + (npos * 16 + c) * 72 + ch * 32 + g * 8);
#pragma unroll
      for (int j = 0; j < 4; j++) {
        const int d = (wpar * 4 + j) * 16 + c;
        const char* vrow = vbase + ch * 8192 + d * 64;
        bf16x8 b1 = *(const bf16x8*)(vrow + g * 16);
        bf16x8 b2 = *(const bf16x8*)(vrow + (g ^ 2) * 16);
        acc[j] = __builtin_amdgcn_mfma_f32_16x16x32_bf16(af, b1, acc[j], 0, 0, 0);
        acc[j] = __builtin_amdgcn_mfma_f32_16x16x32_bf16(af, b2, acc[j], 0, 0, 0);
      }
    }

    asm volatile("s_waitcnt vmcnt(0)" ::: "memory");
    __syncthreads();
  }

  // ---- publish per-wave row-sums, then combine ----
  if (c == 0) {
#pragma unroll
    for (int i = 0; i < 4; i++) Lpart[wpar][npos * 16 + 4 * g + i] = lsum[i];
  }
  __syncthreads();

  // ---- epilogue: out = gamma * acc/L + x ----
  const float gam = gammag[0];
  f32x4 L4;
#pragma unroll
  for (int i = 0; i < 4; i++) {
    const int n = npos * 16 + 4 * g + i;
    L4[i] = Lpart[0][n] + Lpart[1][n];
  }
#pragma unroll
  for (int j = 0; j < 4; j++) {
    const int d = (wpar * 4 + j) * 16 + c;
    const size_t base = ((size_t)(b * 128 + d)) * 4096 + n0 + npos * 16 + 4 * g;
    f32x4 x4 = *(const f32x4*)(xg + base);
    f32x4 o;
#pragma unroll
    for (int i = 0; i < 4; i++) o[i] = gam * (acc[j][i] / L4[i]) + x4[i];
    *(f32x4*)(outg + base) = o;
  }
}

// ---------------------------------------------------------------------------
extern "C" void kernel_launch(void* const* d_in, const int* in_sizes, int n_in,
                              void* d_out, int out_size, void* d_ws, size_t ws_size,
                              hipStream_t stream) {
  (void)in_sizes; (void)n_in; (void)out_size; (void)ws_size;
  const float* x = (const float*)d_in[0];
  const float* Wq = (const float*)d_in[1];
  const float* bq = (const float*)d_in[2];
  const float* Wk = (const float*)d_in[3];
  const float* bk = (const float*)d_in[4];
  const float* Wv = (const float*)d_in[5];
  const float* bv = (const float*)d_in[6];
  const float* gamma = (const float*)d_in[7];
  float* out = (float*)d_out;

  // ws layout: Qg 1MB | Kg 1MB | Vg 8MB  (10MB total)
  short* Qg = (short*)d_ws;
  short* Kg = Qg + (1 << 19);
  short* Vg = Kg + (1 << 19);

  proj_kernel<<<256, 256, 0, stream>>>(x, Wq, bq, Wk, bk, Wv, bv, Qg, Kg, Vg);
  flash_kernel<<<256, 512, 0, stream>>>(Qg, Kg, Vg, x, gamma, out);
}

// Round 4
// 285.124 us; speedup vs baseline: 1.1273x; 1.1273x over previous
//
#include <hip/hip_runtime.h>

// SelfAttention2d: B=4, C=128, EMB=16, N=4096.
// fp32 projections -> interleaved split-bf16 Q/K/V -> MFMA flash attention.
// Exact (hi+lo)x(hi+lo) products: A-operand dword-swap trick means each
// cross-term pair shares ONE B operand. Swapped QK^T keeps P in registers.
// LDS holds only V (2x32KB dbuf, XOR-swizzled, conflict-free b128 reads).
// Waves = (kc key-chunk 0..3) x (dh d-half 0..1): no redundant V reads.

#define NTILE 64  // 4096 / 64 keys per tile
// p = exp(s-16) = exp2(s*log2e - 16*log2e)
#define PEXP(s) exp2f(fmaf((s), 1.44269504f, -23.08312065f))

typedef __attribute__((ext_vector_type(8))) short bf16x8;
typedef __attribute__((ext_vector_type(4))) float f32x4;
typedef __attribute__((ext_vector_type(4))) int i32x4;

__device__ __forceinline__ bf16x8 asbf(i32x4 v) {
  return __builtin_bit_cast(bf16x8, v);
}
__device__ __forceinline__ int cvtpk(float lo, float hi) {
  int r;
  asm("v_cvt_pk_bf16_f32 %0, %1, %2" : "=v"(r) : "v"(lo), "v"(hi));
  return r;
}
__device__ __forceinline__ float lo16f(int u) {
  return __uint_as_float(((unsigned)u) << 16);
}
__device__ __forceinline__ float hi16f(int u) {
  return __uint_as_float(((unsigned)u) & 0xffff0000u);
}
__device__ __forceinline__ void async16(const void* g, void* l) {
  __builtin_amdgcn_global_load_lds(
      (const __attribute__((address_space(1))) void*)g,
      (__attribute__((address_space(3))) void*)l, 16, 0, 0);
}

// ws layouts (per batch b):
//  Qg/Kg: 16B chunk at (b*16384 + g*4096 + n)*16 = [h(e=4g..4g+3) x4 | l x4]
//         (g outer => proj stores and flash loads are contiguous per 16 lanes)
//  Vg: per 64-key tile t (32KB): chunk at ((kc*128+d)*4+gs)*16,
//      gs = gg ^ ((d>>1)&3) (bank swizzle); content = [vh(key kc*16+4gg+j) x4 | vl x4]

// ---------------------------------------------------------------------------
// Projection kernel: 256 blocks = (b, tile t of 64 pixels), 256 threads.
// x staged [c][px] in LDS; lanes-over-pixels so W addresses are wave-uniform
// (scalar loads). Wave dg: 32 V rows + 8 Q-or-K rows.
// ---------------------------------------------------------------------------
__global__ __launch_bounds__(256, 1) void proj_kernel(
    const float* __restrict__ xg, const float* __restrict__ Wq,
    const float* __restrict__ bq, const float* __restrict__ Wk,
    const float* __restrict__ bk, const float* __restrict__ Wv,
    const float* __restrict__ bv, char* __restrict__ Qg,
    char* __restrict__ Kg, char* __restrict__ Vg) {
  __shared__ float xl[8192];  // [c 128][px 64] 32KB; reused as vtmp [d][px]
  const int bid = blockIdx.x;
  const int b = bid >> 6, t = bid & 63, n0 = t << 6;
  const int tid = threadIdx.x;

  for (int i = tid; i < 2048; i += 256) {
    int cc = i >> 4, p4 = (i & 15) << 2;
    f32x4 v = *(const f32x4*)(xg + ((size_t)(b * 128 + cc)) * 4096 + n0 + p4);
    *(f32x4*)&xl[cc * 64 + p4] = v;
  }
  __syncthreads();

  const int px = tid & 63, dg = tid >> 6;  // dg = wave id 0..3
  const float* Wqk = (dg < 2) ? Wq : Wk;
  const int e0 = (dg & 1) * 8;

  float acc[32];
#pragma unroll
  for (int i = 0; i < 32; i++) acc[i] = 0.f;
  float qk[8];
#pragma unroll
  for (int i = 0; i < 8; i++) qk[i] = 0.f;

  for (int c0 = 0; c0 < 128; c0 += 4) {
    float x0 = xl[(c0 + 0) * 64 + px], x1 = xl[(c0 + 1) * 64 + px];
    float x2 = xl[(c0 + 2) * 64 + px], x3 = xl[(c0 + 3) * 64 + px];
#pragma unroll
    for (int dd = 0; dd < 32; dd++) {
      f32x4 wv = *(const f32x4*)(Wv + (size_t)(dg * 32 + dd) * 128 + c0);
      acc[dd] += wv[0] * x0 + wv[1] * x1 + wv[2] * x2 + wv[3] * x3;
    }
#pragma unroll
    for (int ee = 0; ee < 8; ee++) {
      f32x4 wq = *(const f32x4*)(Wqk + (size_t)(e0 + ee) * 128 + c0);
      qk[ee] += wq[0] * x0 + wq[1] * x1 + wq[2] * x2 + wq[3] * x3;
    }
  }

  // ---- Q/K pack + store (2 chunks of 16B per thread, coalesced: g outer) ----
  {
    const float* bqk = (dg < 2) ? bq : bk;
#pragma unroll
    for (int ee = 0; ee < 8; ee++) qk[ee] += bqk[e0 + ee];
    char* QKg = (dg < 2) ? Qg : Kg;
    const int n = n0 + px;
#pragma unroll
    for (int h = 0; h < 2; h++) {
      float v0 = qk[h * 4 + 0], v1 = qk[h * 4 + 1];
      float v2 = qk[h * 4 + 2], v3 = qk[h * 4 + 3];
      int h0 = cvtpk(v0, v1), h1 = cvtpk(v2, v3);
      float r0 = v0 - lo16f(h0), r1 = v1 - hi16f(h0);
      float r2 = v2 - lo16f(h1), r3 = v3 - hi16f(h1);
      int l0 = cvtpk(r0, r1), l1 = cvtpk(r2, r3);
      i32x4 ch = {h0, h1, l0, l1};
      int gq = (dg & 1) * 2 + h;
      *(i32x4*)(QKg + ((size_t)(b * 16384 + gq * 4096 + n)) * 16) = ch;
    }
  }

  // ---- V: add bias, transpose via LDS, pack+store swizzled chunks ----
#pragma unroll
  for (int dd = 0; dd < 32; dd++) acc[dd] += bv[dg * 32 + dd];
  __syncthreads();  // all xl x-reads done
#pragma unroll
  for (int dd = 0; dd < 32; dd++) xl[(dg * 32 + dd) * 64 + px] = acc[dd];
  __syncthreads();

  char* vg_t = Vg + (size_t)b * 2097152 + (size_t)t * 32768;
#pragma unroll
  for (int k = 0; k < 8; k++) {
    int pid = tid + k * 256;  // linear chunk index = (kc*128+d)*4+gs
    int gs = pid & 3, d = (pid >> 2) & 127, kcc = pid >> 9;
    int gg = gs ^ ((d >> 1) & 3);
    f32x4 v = *(const f32x4*)&xl[d * 64 + kcc * 16 + gg * 4];
    int h0 = cvtpk(v[0], v[1]), h1 = cvtpk(v[2], v[3]);
    float r0 = v[0] - lo16f(h0), r1 = v[1] - hi16f(h0);
    float r2 = v[2] - lo16f(h1), r3 = v[3] - hi16f(h1);
    int l0 = cvtpk(r0, r1), l1 = cvtpk(r2, r3);
    i32x4 ch = {h0, h1, l0, l1};
    *(i32x4*)(vg_t + (size_t)pid * 16) = ch;
  }
}

// ---------------------------------------------------------------------------
// Flash kernel. 256 blocks (1/CU), 512 threads (8 waves = 4 kc x 2 dh).
// Block = (batch b, 64 queries). Tile = 64 keys, 64 iterations.
// Wave (kc,dh): S^T = mfma(K[kc], Q[qt]) for qt=0..3 -> lane owns P in regs
// (softmax fully in-register, exact hi/lo split); PV over its 16 keys and
// its 64-d half. No redundant V LDS reads: 32KB/iter total (= tile size).
// Epilogue: ds_add_f32 reduction over the 4 kc waves.
// ---------------------------------------------------------------------------
__global__ __launch_bounds__(512, 2) void flash_kernel(
    const char* __restrict__ Qg, const char* __restrict__ Kg,
    const char* __restrict__ Vg, const float* __restrict__ xg,
    const float* __restrict__ gammag, float* __restrict__ outg) {
  __shared__ __align__(16) char smem[65536];

  const int bid = blockIdx.x;
  const int xcd = bid & 7, slot2 = bid >> 3;
  const int b = xcd >> 1;                    // batch pinned to XCD pair {2b,2b+1}
  const int nt = (slot2 << 1) | (xcd & 1);
  const int n0 = nt << 6;

  const int tid = threadIdx.x;
  const int l = tid & 63, w = tid >> 6;
  const int c = l & 15, g = l >> 4;
  const int kc = w & 3, dh = w >> 2;

  const char* kg_b = Kg + (size_t)b * 262144;
  const char* vg_b = Vg + (size_t)b * 2097152;

  // prologue: stage V tile 0 (2048 x 16B, linear lane order)
#pragma unroll
  for (int k = 0; k < 4; k++) {
    int idx = tid + k * 512;
    async16(vg_b + idx * 16, smem + idx * 16);
  }

  // K fragment (tile 0) + the 4 Q fragments: direct global->reg
  const int krow = kc * 16 + c;
  i32x4 kcur = *(const i32x4*)(kg_b + ((size_t)(g * 4096 + krow)) * 16);
  i32x4 qf[4];
#pragma unroll
  for (int qt = 0; qt < 4; qt++) {
    int n = n0 + qt * 16 + c;
    qf[qt] = *(const i32x4*)(Qg + ((size_t)(b * 16384 + g * 4096 + n)) * 16);
  }

  const f32x4 zero4 = {0.f, 0.f, 0.f, 0.f};
  f32x4 acc[4][4];
#pragma unroll
  for (int qt = 0; qt < 4; qt++)
#pragma unroll
    for (int dt = 0; dt < 4; dt++) acc[qt][dt] = zero4;
  float lsum[4] = {0.f, 0.f, 0.f, 0.f};

  // per-lane invariant V byte offset (d = dh*64 + dt*16 + c):
  // chunk = kc*512 + dh*256 + dt*64 + c*4 + (g ^ ((c>>1)&3)); dt added in-loop
  const int voff = (kc * 512 + dh * 256 + c * 4 + (g ^ ((c >> 1) & 3))) * 16;

  __syncthreads();  // drains prologue vmcnt + joins

  for (int t = 0; t < NTILE; t++) {
    const char* vb = smem + (t & 1) * 32768;

    // stage next V tile into the other buffer (overlaps this iter's compute;
    // the barrier's vmcnt(0) drain at loop end guarantees completion)
    if (t + 1 < NTILE) {
      const char* src = vg_b + (size_t)(t + 1) * 32768;
      char* dst = smem + ((t + 1) & 1) * 32768;
#pragma unroll
      for (int k = 0; k < 4; k++) {
        int idx = tid + k * 512;
        async16(src + idx * 16, dst + idx * 16);
      }
    }
    // prefetch next K fragment
    i32x4 knext = kcur;
    if (t + 1 < NTILE)
      knext = *(const i32x4*)(kg_b +
                              ((size_t)(g * 4096 + (t + 1) * 64 + krow)) * 16);

    // ---- S phase: St = (kh+kl)^T (qh+ql), exact via A dword-swap ----
    i32x4 k2 = {kcur[2], kcur[3], kcur[0], kcur[1]};
    f32x4 st[4];
#pragma unroll
    for (int qt = 0; qt < 4; qt++) {
      f32x4 s = __builtin_amdgcn_mfma_f32_16x16x32_bf16(asbf(kcur), asbf(qf[qt]),
                                                        zero4, 0, 0, 0);
      st[qt] = __builtin_amdgcn_mfma_f32_16x16x32_bf16(asbf(k2), asbf(qf[qt]),
                                                       s, 0, 0, 0);
    }

    // ---- softmax in registers: lane owns keys kc*16+4g..+3, query col c ----
    bf16x8 af1[4], af2[4];
#pragma unroll
    for (int qt = 0; qt < 4; qt++) {
      float p0 = PEXP(st[qt][0]);
      float p1 = PEXP(st[qt][1]);
      float p2 = PEXP(st[qt][2]);
      float p3 = PEXP(st[qt][3]);
      lsum[qt] += (p0 + p1) + (p2 + p3);
      int h0 = cvtpk(p0, p1), h1 = cvtpk(p2, p3);
      float r0 = p0 - lo16f(h0), r1 = p1 - hi16f(h0);
      float r2 = p2 - lo16f(h1), r3 = p3 - hi16f(h1);
      int l0 = cvtpk(r0, r1), l1 = cvtpk(r2, r3);
      i32x4 A1 = {h0, h1, l0, l1};
      i32x4 A2 = {l0, l1, h0, h1};
      af1[qt] = asbf(A1);
      af2[qt] = asbf(A2);
    }

    // ---- PV: one b128 V read per d-tile, 8 MFMAs per read ----
    const char* vlane = vb + voff;
#pragma unroll
    for (int dt = 0; dt < 4; dt++) {
      bf16x8 b1 = *(const bf16x8*)(vlane + dt * 1024);
#pragma unroll
      for (int qt = 0; qt < 4; qt++) {
        acc[qt][dt] =
            __builtin_amdgcn_mfma_f32_16x16x32_bf16(af1[qt], b1, acc[qt][dt], 0, 0, 0);
        acc[qt][dt] =
            __builtin_amdgcn_mfma_f32_16x16x32_bf16(af2[qt], b1, acc[qt][dt], 0, 0, 0);
      }
    }

    kcur = knext;
    __syncthreads();  // drains staging vmcnt; next buffer ready
  }

  // ---- epilogue: reduce over kc waves via LDS, out = gamma*O/L + x ----
  float* Obuf = (float*)smem;            // 64 rows x 129 f32 (padded)
  float* Lbuf = (float*)(smem + 33280);  // 64 f32
  for (int i = tid; i < 64 * 129; i += 512) Obuf[i] = 0.f;
  if (tid < 64) Lbuf[tid] = 0.f;
  __syncthreads();

#pragma unroll
  for (int qt = 0; qt < 4; qt++) {
    float s = lsum[qt];
    s += __shfl_xor(s, 16);
    s += __shfl_xor(s, 32);  // summed over g (4 key-groups)
    if (g == 0 && dh == 0) atomicAdd(&Lbuf[qt * 16 + c], s);  // dh pair is dup
#pragma unroll
    for (int dt = 0; dt < 4; dt++) {
#pragma unroll
      for (int i = 0; i < 4; i++) {
        atomicAdd(&Obuf[(qt * 16 + 4 * g + i) * 129 + dh * 64 + dt * 16 + c],
                  acc[qt][dt][i]);
      }
    }
  }
  __syncthreads();

  const float gam = gammag[0];
#pragma unroll
  for (int k = 0; k < 4; k++) {
    int id = tid + k * 512;
    int q4 = id & 15, d = id >> 4;
    int q0 = q4 * 4;
    size_t base = ((size_t)(b * 128 + d)) * 4096 + n0 + q0;
    f32x4 x4 = *(const f32x4*)(xg + base);
    f32x4 o;
#pragma unroll
    for (int j = 0; j < 4; j++)
      o[j] = gam * (Obuf[(q0 + j) * 129 + d] / Lbuf[q0 + j]) + x4[j];
    *(f32x4*)(outg + base) = o;
  }
}

// ---------------------------------------------------------------------------
extern "C" void kernel_launch(void* const* d_in, const int* in_sizes, int n_in,
                              void* d_out, int out_size, void* d_ws, size_t ws_size,
                              hipStream_t stream) {
  (void)in_sizes; (void)n_in; (void)out_size; (void)ws_size;
  const float* x = (const float*)d_in[0];
  const float* Wq = (const float*)d_in[1];
  const float* bq = (const float*)d_in[2];
  const float* Wk = (const float*)d_in[3];
  const float* bk = (const float*)d_in[4];
  const float* Wv = (const float*)d_in[5];
  const float* bv = (const float*)d_in[6];
  const float* gamma = (const float*)d_in[7];
  float* out = (float*)d_out;

  // ws layout: Qg 1MB | Kg 1MB | Vg 8MB
  char* Qg = (char*)d_ws;
  char* Kg = Qg + (1 << 20);
  char* Vg = Kg + (1 << 20);

  proj_kernel<<<256, 256, 0, stream>>>(x, Wq, bq, Wk, bk, Wv, bv, Qg, Kg, Vg);
  flash_kernel<<<256, 512, 0, stream>>>(Qg, Kg, Vg, x, gamma, out);
}

// Round 5
// 205.369 us; speedup vs baseline: 1.5651x; 1.3883x over previous
//
#include <hip/hip_runtime.h>

// SelfAttention2d: B=4, C=128, EMB=16, N=4096.
// proj: W staged in LDS (kills the 80KB-L1-thrash that made it 128us),
//       4 blocks/CU, exact split-bf16 packing of Q/K/V into ws.
// flash: NO LDS in the main loop. V fragments loaded global->reg per lane
//       (V is L2-resident, 2MB/batch pinned per XCD pair). No barriers;
//       8 free-running waves; per-wave prefetch of next K/V tile.
//       S = (kh+kl)(qh+ql) exact via A dword-swap (2 MFMA);
//       PV = ph*(vh+vl) exact-V via A=[ph|ph], B=[vh|vl] (1 MFMA).

#define NTILE 64  // 4096 / 64 keys per tile
// p = exp(s-16) = exp2(s*log2e - 16*log2e)
#define PEXP(s) exp2f(fmaf((s), 1.44269504f, -23.08312065f))

typedef __attribute__((ext_vector_type(8))) short bf16x8;
typedef __attribute__((ext_vector_type(4))) float f32x4;
typedef __attribute__((ext_vector_type(4))) int i32x4;

__device__ __forceinline__ bf16x8 asbf(i32x4 v) {
  return __builtin_bit_cast(bf16x8, v);
}
__device__ __forceinline__ int cvtpk(float lo, float hi) {
  int r;
  asm("v_cvt_pk_bf16_f32 %0, %1, %2" : "=v"(r) : "v"(lo), "v"(hi));
  return r;
}
__device__ __forceinline__ float lo16f(int u) {
  return __uint_as_float(((unsigned)u) << 16);
}
__device__ __forceinline__ float hi16f(int u) {
  return __uint_as_float(((unsigned)u) & 0xffff0000u);
}

// ws layouts (per batch b):
//  Qg/Kg: 16B chunk at (b*16384 + g*4096 + n)*16 = [h(e=4g..4g+3) x4 | l x4]
//  Vg: per 64-key tile t (32KB): chunk at ((kc*128+d)*4+gs)*16,
//      gs = gg ^ ((d>>1)&3); content = [vh(keys kc*16+4gg..+3, dim d) x4 | vl x4]

// ---------------------------------------------------------------------------
// Projection kernel. grid = 1024 = b(4) x dh(2) x pt(128 tiles of 32 px),
// 256 threads = og(8) x px(32). LDS: W slice (64 Wv rows + 16 Wq|Wk rows,
// 40KB -> exactly 4 blocks/CU). W reads are LDS broadcasts; x read direct.
// ---------------------------------------------------------------------------
__global__ __launch_bounds__(256, 4) void proj_kernel(
    const float* __restrict__ xg, const float* __restrict__ Wq,
    const float* __restrict__ bq, const float* __restrict__ Wk,
    const float* __restrict__ bk, const float* __restrict__ Wv,
    const float* __restrict__ bv, char* __restrict__ Qg,
    char* __restrict__ Kg, char* __restrict__ Vg) {
  __shared__ float wlds[10240];  // [80 rows][128 c]; reused as vtmp [64][32]
  const int bid = blockIdx.x;
  const int pt = bid & 127, dh = (bid >> 7) & 1, b = bid >> 8;
  const int n0 = pt << 5;
  const int tid = threadIdx.x;

  // stage W slice: rows 0..63 = Wv[dh*64+r], rows 64..79 = (dh?Wk:Wq)[r]
  const float* Wqk = dh ? Wk : Wq;
  for (int i = tid; i < 2560; i += 256) {
    int row = i >> 5, c4 = (i & 31) << 2;
    const float* src = (row < 64) ? (Wv + (size_t)(dh * 64 + row) * 128 + c4)
                                  : (Wqk + (size_t)(row - 64) * 128 + c4);
    *(f32x4*)&wlds[row * 128 + c4] = *(const f32x4*)src;
  }
  __syncthreads();

  const int px = tid & 31, og = tid >> 5;
  const float* xb = xg + (size_t)b * 524288 + n0 + px;

  float av[8];
#pragma unroll
  for (int r = 0; r < 8; r++) av[r] = 0.f;
  float aq[4] = {0.f, 0.f, 0.f, 0.f};

  for (int c0 = 0; c0 < 128; c0 += 4) {
    float x0 = xb[(size_t)(c0 + 0) * 4096];
    float x1 = xb[(size_t)(c0 + 1) * 4096];
    float x2 = xb[(size_t)(c0 + 2) * 4096];
    float x3 = xb[(size_t)(c0 + 3) * 4096];
#pragma unroll
    for (int r = 0; r < 8; r++) {
      const float* wr = &wlds[(og * 8 + r) * 128 + c0];
      av[r] += wr[0] * x0 + wr[1] * x1 + wr[2] * x2 + wr[3] * x3;
    }
    if (og < 4) {  // wave-uniform branch (waves 0,1 take it)
#pragma unroll
      for (int ee = 0; ee < 4; ee++) {
        const float* wr = &wlds[(64 + og * 4 + ee) * 128 + c0];
        aq[ee] += wr[0] * x0 + wr[1] * x1 + wr[2] * x2 + wr[3] * x3;
      }
    }
  }

  // ---- Q/K pack + store (exact hi/lo; coalesced 16B per lane) ----
  if (og < 4) {
    const float* bqk = dh ? bk : bq;
    float v0 = aq[0] + bqk[og * 4 + 0], v1 = aq[1] + bqk[og * 4 + 1];
    float v2 = aq[2] + bqk[og * 4 + 2], v3 = aq[3] + bqk[og * 4 + 3];
    int h0 = cvtpk(v0, v1), h1 = cvtpk(v2, v3);
    float r0 = v0 - lo16f(h0), r1 = v1 - hi16f(h0);
    float r2 = v2 - lo16f(h1), r3 = v3 - hi16f(h1);
    int l0 = cvtpk(r0, r1), l1 = cvtpk(r2, r3);
    i32x4 ch = {h0, h1, l0, l1};
    char* QKg = dh ? Kg : Qg;
    *(i32x4*)(QKg + ((size_t)(b * 16384 + og * 4096 + n0 + px)) * 16) = ch;
  }

  // ---- V: bias, transpose via LDS (overlaying wlds), pack+store ----
  const int d0 = dh * 64 + og * 8;
#pragma unroll
  for (int r = 0; r < 8; r++) av[r] += bv[d0 + r];
  __syncthreads();  // all W reads done; safe to overlay
#pragma unroll
  for (int r = 0; r < 8; r++) wlds[(og * 8 + r) * 32 + px] = av[r];
  __syncthreads();

  char* vg_t = Vg + (size_t)b * 2097152 + (size_t)(pt >> 1) * 32768;
#pragma unroll
  for (int k = 0; k < 2; k++) {
    int pid = tid + k * 256;      // block-local chunk id
    int gs = pid & 3, d1 = (pid >> 2) & 63, kcl = pid >> 8;
    int d = dh * 64 + d1;
    int gg = gs ^ ((d >> 1) & 3);
    f32x4 v = *(const f32x4*)&wlds[d1 * 32 + kcl * 16 + gg * 4];
    int h0 = cvtpk(v[0], v[1]), h1 = cvtpk(v[2], v[3]);
    float r0 = v[0] - lo16f(h0), r1 = v[1] - hi16f(h0);
    float r2 = v[2] - lo16f(h1), r3 = v[3] - hi16f(h1);
    int l0 = cvtpk(r0, r1), l1 = cvtpk(r2, r3);
    i32x4 ch = {h0, h1, l0, l1};
    int kc = (pt & 1) * 2 + kcl;
    *(i32x4*)(vg_t + ((size_t)((kc * 128 + d) * 4 + gs)) * 16) = ch;
  }
}

// ---------------------------------------------------------------------------
// Flash kernel. 256 blocks (1/CU), 512 threads (8 waves = 4 kc x 2 dh).
// No LDS, no barriers in the main loop: each wave loads its own K fragment
// and 4 V fragments per 64-key tile directly from global (L2-resident),
// prefetched one tile ahead. Softmax in registers (swapped QK^T).
// Epilogue: LDS reduction over the 4 kc waves.
// ---------------------------------------------------------------------------
__global__ __launch_bounds__(512, 2) void flash_kernel(
    const char* __restrict__ Qg, const char* __restrict__ Kg,
    const char* __restrict__ Vg, const float* __restrict__ xg,
    const float* __restrict__ gammag, float* __restrict__ outg) {
  __shared__ float red_O[64 * 129];  // padded rows
  __shared__ float red_L[64];

  const int bid = blockIdx.x;
  const int xcd = bid & 7, slot2 = bid >> 3;
  const int b = xcd >> 1;  // batch pinned to XCD pair {2b,2b+1}
  const int nt = (slot2 << 1) | (xcd & 1);
  const int n0 = nt << 6;

  const int tid = threadIdx.x;
  const int l = tid & 63, w = tid >> 6;
  const int c = l & 15, g = l >> 4;
  const int kc = w & 3, dh = w >> 2;

  const char* kg_b = Kg + (size_t)b * 262144;
  const char* vg_b = Vg + (size_t)b * 2097152;

  // per-lane V fragment base: chunk kc*512 + dh*256 + dt*64 + c*4 + swz(g)
  const char* vlane =
      vg_b + ((size_t)(kc * 512 + dh * 256 + c * 4 + (g ^ ((c >> 1) & 3)))) * 16;

  const int krow = kc * 16 + c;
  i32x4 kcur = *(const i32x4*)(kg_b + ((size_t)(g * 4096 + krow)) * 16);
  i32x4 qf[4];
#pragma unroll
  for (int qt = 0; qt < 4; qt++) {
    int n = n0 + qt * 16 + c;
    qf[qt] = *(const i32x4*)(Qg + ((size_t)(b * 16384 + g * 4096 + n)) * 16);
  }

  // tile-0 V fragments
  i32x4 vc0 = *(const i32x4*)(vlane + 0);
  i32x4 vc1 = *(const i32x4*)(vlane + 1024);
  i32x4 vc2 = *(const i32x4*)(vlane + 2048);
  i32x4 vc3 = *(const i32x4*)(vlane + 3072);

  const f32x4 zero4 = {0.f, 0.f, 0.f, 0.f};
  f32x4 acc[4][4];
#pragma unroll
  for (int qt = 0; qt < 4; qt++)
#pragma unroll
    for (int dt = 0; dt < 4; dt++) acc[qt][dt] = zero4;
  float lsum[4] = {0.f, 0.f, 0.f, 0.f};

  for (int t = 0; t < NTILE; t++) {
    // ---- prefetch next tile (K + 4 V fragments) into registers ----
    i32x4 knext = kcur, vn0 = vc0, vn1 = vc1, vn2 = vc2, vn3 = vc3;
    if (t + 1 < NTILE) {
      const char* vnb = vlane + (size_t)(t + 1) * 32768;
      vn0 = *(const i32x4*)(vnb + 0);
      vn1 = *(const i32x4*)(vnb + 1024);
      vn2 = *(const i32x4*)(vnb + 2048);
      vn3 = *(const i32x4*)(vnb + 3072);
      knext = *(const i32x4*)(kg_b +
                              ((size_t)(g * 4096 + (t + 1) * 64 + krow)) * 16);
    }

    // ---- S phase: St = (kh+kl)^T (qh+ql), exact via A dword-swap ----
    i32x4 k2 = {kcur[2], kcur[3], kcur[0], kcur[1]};
    f32x4 st[4];
    __builtin_amdgcn_s_setprio(1);
#pragma unroll
    for (int qt = 0; qt < 4; qt++) {
      f32x4 s = __builtin_amdgcn_mfma_f32_16x16x32_bf16(asbf(kcur), asbf(qf[qt]),
                                                        zero4, 0, 0, 0);
      st[qt] = __builtin_amdgcn_mfma_f32_16x16x32_bf16(asbf(k2), asbf(qf[qt]), s,
                                                       0, 0, 0);
    }
    __builtin_amdgcn_s_setprio(0);

    // ---- softmax in registers: lane owns keys kc*16+4g..+3, query col c ----
    bf16x8 af[4];
#pragma unroll
    for (int qt = 0; qt < 4; qt++) {
      float p0 = PEXP(st[qt][0]);
      float p1 = PEXP(st[qt][1]);
      float p2 = PEXP(st[qt][2]);
      float p3 = PEXP(st[qt][3]);
      lsum[qt] += (p0 + p1) + (p2 + p3);
      int h0 = cvtpk(p0, p1), h1 = cvtpk(p2, p3);
      i32x4 A = {h0, h1, h0, h1};  // [ph|ph]: with B=[vh|vl] -> ph*(vh+vl)
      af[qt] = asbf(A);
    }

    // ---- PV: 1 MFMA per (qt,dt); V exact (hi+lo summed inside K=32) ----
    __builtin_amdgcn_s_setprio(1);
#pragma unroll
    for (int qt = 0; qt < 4; qt++) {
      acc[qt][0] = __builtin_amdgcn_mfma_f32_16x16x32_bf16(af[qt], asbf(vc0),
                                                           acc[qt][0], 0, 0, 0);
      acc[qt][1] = __builtin_amdgcn_mfma_f32_16x16x32_bf16(af[qt], asbf(vc1),
                                                           acc[qt][1], 0, 0, 0);
      acc[qt][2] = __builtin_amdgcn_mfma_f32_16x16x32_bf16(af[qt], asbf(vc2),
                                                           acc[qt][2], 0, 0, 0);
      acc[qt][3] = __builtin_amdgcn_mfma_f32_16x16x32_bf16(af[qt], asbf(vc3),
                                                           acc[qt][3], 0, 0, 0);
    }
    __builtin_amdgcn_s_setprio(0);

    kcur = knext;
    vc0 = vn0; vc1 = vn1; vc2 = vn2; vc3 = vn3;
  }

  // ---- epilogue: reduce over kc waves via LDS, out = gamma*O/L + x ----
  for (int i = tid; i < 64 * 129; i += 512) red_O[i] = 0.f;
  if (tid < 64) red_L[tid] = 0.f;
  __syncthreads();

#pragma unroll
  for (int qt = 0; qt < 4; qt++) {
    float s = lsum[qt];
    s += __shfl_xor(s, 16);
    s += __shfl_xor(s, 32);  // summed over the 4 g key-groups
    if (g == 0 && dh == 0) atomicAdd(&red_L[qt * 16 + c], s);
#pragma unroll
    for (int dt = 0; dt < 4; dt++) {
#pragma unroll
      for (int i = 0; i < 4; i++) {
        atomicAdd(&red_O[(qt * 16 + 4 * g + i) * 129 + dh * 64 + dt * 16 + c],
                  acc[qt][dt][i]);
      }
    }
  }
  __syncthreads();

  const float gam = gammag[0];
#pragma unroll
  for (int k = 0; k < 4; k++) {
    int id = tid + k * 512;
    int q4 = id & 15, d = id >> 4;
    int q0 = q4 * 4;
    size_t base = ((size_t)(b * 128 + d)) * 4096 + n0 + q0;
    f32x4 x4 = *(const f32x4*)(xg + base);
    f32x4 o;
#pragma unroll
    for (int j = 0; j < 4; j++)
      o[j] = gam * (red_O[(q0 + j) * 129 + d] / red_L[q0 + j]) + x4[j];
    *(f32x4*)(outg + base) = o;
  }
}

// ---------------------------------------------------------------------------
extern "C" void kernel_launch(void* const* d_in, const int* in_sizes, int n_in,
                              void* d_out, int out_size, void* d_ws, size_t ws_size,
                              hipStream_t stream) {
  (void)in_sizes; (void)n_in; (void)out_size; (void)ws_size;
  const float* x = (const float*)d_in[0];
  const float* Wq = (const float*)d_in[1];
  const float* bq = (const float*)d_in[2];
  const float* Wk = (const float*)d_in[3];
  const float* bk = (const float*)d_in[4];
  const float* Wv = (const float*)d_in[5];
  const float* bv = (const float*)d_in[6];
  const float* gamma = (const float*)d_in[7];
  float* out = (float*)d_out;

  // ws layout: Qg 1MB | Kg 1MB | Vg 8MB
  char* Qg = (char*)d_ws;
  char* Kg = Qg + (1 << 20);
  char* Vg = Kg + (1 << 20);

  proj_kernel<<<1024, 256, 0, stream>>>(x, Wq, bq, Wk, bk, Wv, bv, Qg, Kg, Vg);
  flash_kernel<<<256, 512, 0, stream>>>(Qg, Kg, Vg, x, gamma, out);
}

// Round 7
// 182.257 us; speedup vs baseline: 1.7636x; 1.1268x over previous
//
#include <hip/hip_runtime.h>

// SelfAttention2d: B=4, C=128, EMB=16, N=4096.
// proj: x+W staged to LDS via one global_load_lds burst (latency paid once),
//       then pure LDS-fed FMA. 2 blocks/CU.
// flash: 512 blocks x 32 queries (2 blocks/CU, 16 waves/CU), no LDS/barriers
//       in main loop; V/K global->reg with DEPTH-2 register prefetch
//       (unroll-2, two named sets). S=(kh+kl)(qh+ql) exact via A dword-swap;
//       PV = ph*(vh+vl) exact-V in one MFMA (A=[ph|ph], B=[vh|vl]).
// R6 fix: proj x-staging chunk math was idx>>2/(idx&3) (OOB reads, GPU
// fault). A 64-px row is 16 chunks: cc=idx>>4, p4=(idx&15)*4.

#define PEXP(s) exp2f(fmaf((s), 1.44269504f, -23.08312065f))  // exp(s-16)

typedef __attribute__((ext_vector_type(8))) short bf16x8;
typedef __attribute__((ext_vector_type(4))) float f32x4;
typedef __attribute__((ext_vector_type(4))) int i32x4;

__device__ __forceinline__ bf16x8 asbf(i32x4 v) {
  return __builtin_bit_cast(bf16x8, v);
}
__device__ __forceinline__ int cvtpk(float lo, float hi) {
  int r;
  asm("v_cvt_pk_bf16_f32 %0, %1, %2" : "=v"(r) : "v"(lo), "v"(hi));
  return r;
}
__device__ __forceinline__ float lo16f(int u) {
  return __uint_as_float(((unsigned)u) << 16);
}
__device__ __forceinline__ float hi16f(int u) {
  return __uint_as_float(((unsigned)u) & 0xffff0000u);
}
__device__ __forceinline__ void async16(const void* g, void* l) {
  __builtin_amdgcn_global_load_lds(
      (const __attribute__((address_space(1))) void*)g,
      (__attribute__((address_space(3))) void*)l, 16, 0, 0);
}

// ws layouts (per batch b), identical to R5 (validated):
//  Qg/Kg: 16B chunk at (b*16384 + g*4096 + n)*16 = [h(e=4g..4g+3) x4 | l x4]
//  Vg: per 64-key tile t (32KB): chunk at ((kc*128+d)*4+gs)*16,
//      gs = gg ^ ((d>>1)&3); content = [vh(keys kc*16+4gg..+3, dim d) x4 | vl x4]

// ---------------------------------------------------------------------------
// Projection. grid 512: xcd=bid&7 -> b=xcd>>1, dh=xcd&1 (batch pinned to its
// XCD pair, same as flash); pt=bid>>3 (64-px tile). 256 thr = og(4 waves)xpx(64).
// LDS: xl 32KB [c128][px64] + wl 40KB [80 rows][c128]; vtmp overlays xl.
// ---------------------------------------------------------------------------
__global__ __launch_bounds__(256, 2) void proj_kernel(
    const float* __restrict__ xg, const float* __restrict__ Wq,
    const float* __restrict__ bq, const float* __restrict__ Wk,
    const float* __restrict__ bk, const float* __restrict__ Wv,
    const float* __restrict__ bv, char* __restrict__ Qg,
    char* __restrict__ Kg, char* __restrict__ Vg) {
  __shared__ __align__(16) float xl[8192];   // 32KB
  __shared__ __align__(16) float wl[10240];  // 40KB
  const int bid = blockIdx.x;
  const int xcd = bid & 7, b = xcd >> 1, dh = xcd & 1, pt = bid >> 3;
  const int n0 = pt << 6;
  const int tid = threadIdx.x;

  // ---- one async burst: x tile (2048 chunks) + W slice (2560 chunks) ----
  const float* Wqk = dh ? Wk : Wq;
#pragma unroll
  for (int k = 0; k < 8; k++) {
    int idx = tid + k * 256;  // chunk: channel = idx>>4, 16B (4 px) each
    int cc = idx >> 4, p4 = (idx & 15) << 2;
    const float* src = xg + ((size_t)(b * 128 + cc)) * 4096 + n0 + p4;
    async16(src, (char*)xl + idx * 16);
  }
#pragma unroll
  for (int k = 0; k < 10; k++) {
    int j = tid + k * 256;  // row = j>>5 (0..79), 16B along c
    int row = j >> 5, c4 = (j & 31) * 4;
    const float* src = (k < 8) ? (Wv + (size_t)(dh * 64 + row) * 128 + c4)
                               : (Wqk + (size_t)(row - 64) * 128 + c4);
    async16(src, (char*)wl + j * 16);
  }
  asm volatile("s_waitcnt vmcnt(0)" ::: "memory");
  __syncthreads();

  const int px = tid & 63, og = tid >> 6;  // og = wave id

  float av[16];
#pragma unroll
  for (int i = 0; i < 16; i++) av[i] = 0.f;
  float aq[4] = {0.f, 0.f, 0.f, 0.f};

  for (int c0 = 0; c0 < 128; c0 += 4) {
    float x0 = xl[(c0 + 0) * 64 + px];
    float x1 = xl[(c0 + 1) * 64 + px];
    float x2 = xl[(c0 + 2) * 64 + px];
    float x3 = xl[(c0 + 3) * 64 + px];
#pragma unroll
    for (int r = 0; r < 16; r++) {
      const float* wr = &wl[(og * 16 + r) * 128 + c0];
      av[r] += wr[0] * x0 + wr[1] * x1 + wr[2] * x2 + wr[3] * x3;
    }
#pragma unroll
    for (int ee = 0; ee < 4; ee++) {
      const float* wr = &wl[(64 + og * 4 + ee) * 128 + c0];
      aq[ee] += wr[0] * x0 + wr[1] * x1 + wr[2] * x2 + wr[3] * x3;
    }
  }

  // ---- Q/K pack + store (g = og; coalesced 16B/lane) ----
  {
    const float* bqk = dh ? bk : bq;
    float v0 = aq[0] + bqk[og * 4 + 0], v1 = aq[1] + bqk[og * 4 + 1];
    float v2 = aq[2] + bqk[og * 4 + 2], v3 = aq[3] + bqk[og * 4 + 3];
    int h0 = cvtpk(v0, v1), h1 = cvtpk(v2, v3);
    float r0 = v0 - lo16f(h0), r1 = v1 - hi16f(h0);
    float r2 = v2 - lo16f(h1), r3 = v3 - hi16f(h1);
    int l0 = cvtpk(r0, r1), l1 = cvtpk(r2, r3);
    i32x4 ch = {h0, h1, l0, l1};
    char* QKg = dh ? Kg : Qg;
    *(i32x4*)(QKg + ((size_t)(b * 16384 + og * 4096 + n0 + px)) * 16) = ch;
  }

  // ---- V: bias, transpose via vtmp (overlay xl), pack+store swizzled ----
  const int d0 = dh * 64 + og * 16;
  __syncthreads();  // all xl/wl reads done
#pragma unroll
  for (int r = 0; r < 16; r++) xl[(og * 16 + r) * 64 + px] = av[r] + bv[d0 + r];
  __syncthreads();

  char* vg_t = Vg + (size_t)b * 2097152 + (size_t)pt * 32768;
#pragma unroll
  for (int k = 0; k < 4; k++) {
    int id = tid + k * 256;  // chunk id within dh-half
    int gs = id & 3, d1 = (id >> 2) & 63, kc = id >> 8;
    int d = dh * 64 + d1;
    int gg = gs ^ ((d >> 1) & 3);
    f32x4 v = *(const f32x4*)&xl[d1 * 64 + kc * 16 + gg * 4];
    int h0 = cvtpk(v[0], v[1]), h1 = cvtpk(v[2], v[3]);
    float r0 = v[0] - lo16f(h0), r1 = v[1] - hi16f(h0);
    float r2 = v[2] - lo16f(h1), r3 = v[3] - hi16f(h1);
    int l0 = cvtpk(r0, r1), l1 = cvtpk(r2, r3);
    i32x4 ch = {h0, h1, l0, l1};
    *(i32x4*)(vg_t + ((size_t)((kc * 128 + d) * 4 + gs)) * 16) = ch;
  }
}

// ---------------------------------------------------------------------------
// Flash. 512 blocks (2/CU) x 512 thr (8 waves = 4 kc x 2 dh), 32 queries/blk.
// Main loop: no LDS, no barriers; depth-2 register prefetch via unroll-2.
// ---------------------------------------------------------------------------
#define COMPUTE(KF, V0, V1, V2, V3)                                            \
  {                                                                            \
    i32x4 k2 = {KF[2], KF[3], KF[0], KF[1]};                                   \
    __builtin_amdgcn_s_setprio(1);                                             \
    f32x4 s0 = __builtin_amdgcn_mfma_f32_16x16x32_bf16(asbf(KF), asbf(qf0),    \
                                                       zero4, 0, 0, 0);        \
    s0 = __builtin_amdgcn_mfma_f32_16x16x32_bf16(asbf(k2), asbf(qf0), s0, 0,   \
                                                 0, 0);                        \
    f32x4 s1 = __builtin_amdgcn_mfma_f32_16x16x32_bf16(asbf(KF), asbf(qf1),    \
                                                       zero4, 0, 0, 0);        \
    s1 = __builtin_amdgcn_mfma_f32_16x16x32_bf16(asbf(k2), asbf(qf1), s1, 0,   \
                                                 0, 0);                        \
    __builtin_amdgcn_s_setprio(0);                                             \
    bf16x8 a0, a1;                                                             \
    {                                                                          \
      float p0 = PEXP(s0[0]), p1 = PEXP(s0[1]), p2 = PEXP(s0[2]),              \
            p3 = PEXP(s0[3]);                                                  \
      lsum0 += (p0 + p1) + (p2 + p3);                                          \
      int h0 = cvtpk(p0, p1), h1 = cvtpk(p2, p3);                              \
      i32x4 A = {h0, h1, h0, h1};                                              \
      a0 = asbf(A);                                                            \
    }                                                                          \
    {                                                                          \
      float p0 = PEXP(s1[0]), p1 = PEXP(s1[1]), p2 = PEXP(s1[2]),              \
            p3 = PEXP(s1[3]);                                                  \
      lsum1 += (p0 + p1) + (p2 + p3);                                          \
      int h0 = cvtpk(p0, p1), h1 = cvtpk(p2, p3);                              \
      i32x4 A = {h0, h1, h0, h1};                                              \
      a1 = asbf(A);                                                            \
    }                                                                          \
    __builtin_amdgcn_s_setprio(1);                                             \
    acc[0][0] = __builtin_amdgcn_mfma_f32_16x16x32_bf16(a0, asbf(V0),          \
                                                        acc[0][0], 0, 0, 0);   \
    acc[0][1] = __builtin_amdgcn_mfma_f32_16x16x32_bf16(a0, asbf(V1),          \
                                                        acc[0][1], 0, 0, 0);   \
    acc[0][2] = __builtin_amdgcn_mfma_f32_16x16x32_bf16(a0, asbf(V2),          \
                                                        acc[0][2], 0, 0, 0);   \
    acc[0][3] = __builtin_amdgcn_mfma_f32_16x16x32_bf16(a0, asbf(V3),          \
                                                        acc[0][3], 0, 0, 0);   \
    acc[1][0] = __builtin_amdgcn_mfma_f32_16x16x32_bf16(a1, asbf(V0),          \
                                                        acc[1][0], 0, 0, 0);   \
    acc[1][1] = __builtin_amdgcn_mfma_f32_16x16x32_bf16(a1, asbf(V1),          \
                                                        acc[1][1], 0, 0, 0);   \
    acc[1][2] = __builtin_amdgcn_mfma_f32_16x16x32_bf16(a1, asbf(V2),          \
                                                        acc[1][2], 0, 0, 0);   \
    acc[1][3] = __builtin_amdgcn_mfma_f32_16x16x32_bf16(a1, asbf(V3),          \
                                                        acc[1][3], 0, 0, 0);   \
    __builtin_amdgcn_s_setprio(0);                                             \
  }

#define LOADSET(KF, V0, V1, V2, V3, tt)                                        \
  {                                                                            \
    const char* vp = vlane + (size_t)(tt)*32768;                               \
    V0 = *(const i32x4*)(vp);                                                  \
    V1 = *(const i32x4*)(vp + 1024);                                           \
    V2 = *(const i32x4*)(vp + 2048);                                           \
    V3 = *(const i32x4*)(vp + 3072);                                           \
    KF = *(const i32x4*)(kg_b + ((size_t)(g * 4096 + (tt)*64 + krow)) * 16);   \
  }

__global__ __launch_bounds__(512, 4) void flash_kernel(
    const char* __restrict__ Qg, const char* __restrict__ Kg,
    const char* __restrict__ Vg, const float* __restrict__ xg,
    const float* __restrict__ gammag, float* __restrict__ outg) {
  __shared__ float red_O[32 * 129];
  __shared__ float red_L[32];

  const int bid = blockIdx.x;
  const int xcd = bid & 7;
  const int b = xcd >> 1;                       // batch pinned to XCD pair
  const int nt = ((bid >> 3) << 1) | (xcd & 1); // 0..127
  const int n0 = nt << 5;

  const int tid = threadIdx.x;
  const int l = tid & 63, w = tid >> 6;
  const int c = l & 15, g = l >> 4;
  const int kc = w & 3, dh = w >> 2;

  const char* kg_b = Kg + (size_t)b * 262144;
  const char* vg_b = Vg + (size_t)b * 2097152;
  const char* vlane =
      vg_b + ((size_t)(kc * 512 + dh * 256 + c * 4 + (g ^ ((c >> 1) & 3)))) * 16;
  const int krow = kc * 16 + c;

  const i32x4 qf0 =
      *(const i32x4*)(Qg + ((size_t)(b * 16384 + g * 4096 + n0 + c)) * 16);
  const i32x4 qf1 =
      *(const i32x4*)(Qg + ((size_t)(b * 16384 + g * 4096 + n0 + 16 + c)) * 16);

  const f32x4 zero4 = {0.f, 0.f, 0.f, 0.f};
  f32x4 acc[2][4];
#pragma unroll
  for (int qt = 0; qt < 2; qt++)
#pragma unroll
    for (int dt = 0; dt < 4; dt++) acc[qt][dt] = zero4;
  float lsum0 = 0.f, lsum1 = 0.f;

  i32x4 ka, va0, va1, va2, va3;
  i32x4 kb, vb0, vb1, vb2, vb3;
  LOADSET(ka, va0, va1, va2, va3, 0);
  LOADSET(kb, vb0, vb1, vb2, vb3, 1);

  for (int t = 0; t < 64; t += 2) {
    COMPUTE(ka, va0, va1, va2, va3);
    {
      int t2 = (t + 2 < 64) ? t + 2 : 63;
      LOADSET(ka, va0, va1, va2, va3, t2);
    }
    COMPUTE(kb, vb0, vb1, vb2, vb3);
    {
      int t3 = (t + 3 < 64) ? t + 3 : 63;
      LOADSET(kb, vb0, vb1, vb2, vb3, t3);
    }
  }

  // ---- epilogue: reduce over kc waves via LDS, out = gamma*O/L + x ----
  for (int i = tid; i < 32 * 129; i += 512) red_O[i] = 0.f;
  if (tid < 32) red_L[tid] = 0.f;
  __syncthreads();

  {
    float s = lsum0;
    s += __shfl_xor(s, 16);
    s += __shfl_xor(s, 32);
    if (g == 0 && dh == 0) atomicAdd(&red_L[c], s);
    s = lsum1;
    s += __shfl_xor(s, 16);
    s += __shfl_xor(s, 32);
    if (g == 0 && dh == 0) atomicAdd(&red_L[16 + c], s);
  }
#pragma unroll
  for (int qt = 0; qt < 2; qt++) {
#pragma unroll
    for (int dt = 0; dt < 4; dt++) {
#pragma unroll
      for (int i = 0; i < 4; i++) {
        atomicAdd(&red_O[(qt * 16 + 4 * g + i) * 129 + dh * 64 + dt * 16 + c],
                  acc[qt][dt][i]);
      }
    }
  }
  __syncthreads();

  const float gam = gammag[0];
#pragma unroll
  for (int k = 0; k < 2; k++) {
    int id = tid + k * 512;
    int q4 = id & 7, d = id >> 3;  // 8 q-groups of 4, 128 dims
    int q0 = q4 * 4;
    size_t base = ((size_t)(b * 128 + d)) * 4096 + n0 + q0;
    f32x4 x4 = *(const f32x4*)(xg + base);
    f32x4 o;
#pragma unroll
    for (int j = 0; j < 4; j++)
      o[j] = gam * (red_O[(q0 + j) * 129 + d] / red_L[q0 + j]) + x4[j];
    *(f32x4*)(outg + base) = o;
  }
}

// ---------------------------------------------------------------------------
extern "C" void kernel_launch(void* const* d_in, const int* in_sizes, int n_in,
                              void* d_out, int out_size, void* d_ws, size_t ws_size,
                              hipStream_t stream) {
  (void)in_sizes; (void)n_in; (void)out_size; (void)ws_size;
  const float* x = (const float*)d_in[0];
  const float* Wq = (const float*)d_in[1];
  const float* bq = (const float*)d_in[2];
  const float* Wk = (const float*)d_in[3];
  const float* bk = (const float*)d_in[4];
  const float* Wv = (const float*)d_in[5];
  const float* bv = (const float*)d_in[6];
  const float* gamma = (const float*)d_in[7];
  float* out = (float*)d_out;

  // ws layout: Qg 1MB | Kg 1MB | Vg 8MB
  char* Qg = (char*)d_ws;
  char* Kg = Qg + (1 << 20);
  char* Vg = Kg + (1 << 20);

  proj_kernel<<<512, 256, 0, stream>>>(x, Wq, bq, Wk, bk, Wv, bv, Qg, Kg, Vg);
  flash_kernel<<<512, 512, 0, stream>>>(Qg, Kg, Vg, x, gamma, out);
}

// Round 8
// 175.196 us; speedup vs baseline: 1.8347x; 1.0403x over previous
//
#include <hip/hip_runtime.h>

// SelfAttention2d: B=4, C=128, EMB=16, N=4096.
// proj: ONE MFMA kernel. x tile (fp32) + split-bf16 W-fragments staged in
//       LDS; exact (h+l)(h'+l') products via 2 MFMAs (operand dword-swap).
//       Writes Qg/Kg/Vg in flash's layouts (Vg now unswizzled, d-innermost).
// flash: 256 blocks x 64 queries, 8 waves = kc(4) x qh(2): softmax computed
//       exactly once (no dh duplication). No LDS/barriers in main loop;
//       V/K global->reg depth-2 prefetch, 32-bit voffsets.
//       S=(kh+kl)(qh+ql) exact via dword-swap; PV=ph*(vh+vl) one MFMA.

#define PEXP(s) exp2f(fmaf((s), 1.44269504f, -23.08312065f))  // exp(s-16)

typedef __attribute__((ext_vector_type(8))) short bf16x8;
typedef __attribute__((ext_vector_type(4))) float f32x4;
typedef __attribute__((ext_vector_type(4))) int i32x4;

__device__ __forceinline__ bf16x8 asbf(i32x4 v) {
  return __builtin_bit_cast(bf16x8, v);
}
__device__ __forceinline__ int cvtpk(float lo, float hi) {
  int r;
  asm("v_cvt_pk_bf16_f32 %0, %1, %2" : "=v"(r) : "v"(lo), "v"(hi));
  return r;
}
__device__ __forceinline__ float lo16f(int u) {
  return __uint_as_float(((unsigned)u) << 16);
}
__device__ __forceinline__ float hi16f(int u) {
  return __uint_as_float(((unsigned)u) & 0xffff0000u);
}
__device__ __forceinline__ void async16(const void* g, void* l) {
  __builtin_amdgcn_global_load_lds(
      (const __attribute__((address_space(1))) void*)g,
      (__attribute__((address_space(3))) void*)l, 16, 0, 0);
}
// pack fp32x4 -> [h0 h1 l0 l1] dwords (4 bf16 hi, 4 bf16 lo residual)
__device__ __forceinline__ i32x4 packhl(float v0, float v1, float v2, float v3) {
  int h0 = cvtpk(v0, v1), h1 = cvtpk(v2, v3);
  int l0 = cvtpk(v0 - lo16f(h0), v1 - hi16f(h0));
  int l1 = cvtpk(v2 - lo16f(h1), v3 - hi16f(h1));
  i32x4 r = {h0, h1, l0, l1};
  return r;
}

// ws layouts (per batch b):
//  Qg/Kg: 16B chunk at (b*16384 + g*4096 + n)*16 = [h(e=4g..4g+3) x4 | l x4]
//  Vg: per 64-key tile t (32KB): chunk at ((kc*4+gg)*128 + d)*16,
//      content = [vh(keys kc*16+4gg+j, dim d) j=0..3 | vl x4]   (no swizzle)

// ---------------------------------------------------------------------------
// Projection (MFMA). grid 256 = xcd(8: b=xcd>>1) x Pg(64 per b), 256 thr
// (4 waves). Block covers 64 px (4 col-tiles of 16; wave w owns one).
// LDS: xl [128 c][64 px] fp32 32KB + wl 5120 wfrag chunks 80KB = 112KB.
// Per wave: for m(8 K-chunks): build x-frag in reg (exact hi/lo), then for
// r(10 rowtiles: 8 V + Q + K): 2 MFMAs (dword-swap exact product).
// ---------------------------------------------------------------------------
__global__ __launch_bounds__(256, 1) void proj_kernel(
    const float* __restrict__ xg, const float* __restrict__ Wq,
    const float* __restrict__ bq, const float* __restrict__ Wk,
    const float* __restrict__ bk, const float* __restrict__ Wv,
    const float* __restrict__ bv, char* __restrict__ Qg,
    char* __restrict__ Kg, char* __restrict__ Vg) {
  __shared__ __align__(16) float xl[8192];    // [c 128][px 64]
  __shared__ __align__(16) char wl[81920];    // 5120 wfrag chunks
  const int bid = blockIdx.x;
  const int xcd = bid & 7, b = xcd >> 1;
  const int Pg = ((bid >> 3) << 1) | (xcd & 1);  // 0..63
  const int n0 = Pg << 6;
  const int tid = threadIdx.x;

  // ---- stage x tile: 2048 async 16B chunks ----
#pragma unroll
  for (int k = 0; k < 8; k++) {
    int idx = tid + k * 256;
    int cc = idx >> 4, p4 = (idx & 15) << 2;
    async16(xg + ((size_t)(b * 128 + cc)) * 4096 + n0 + p4,
            (char*)xl + idx * 16);
  }
  // ---- build W fragments into LDS: 5120 chunks, 20/thread ----
#pragma unroll
  for (int k = 0; k < 20; k++) {
    int wid = tid + k * 256;
    int dd = wid & 15, g = (wid >> 4) & 3, m = (wid >> 6) & 7, r = wid >> 9;
    const float* row = (r < 8) ? (Wv + (size_t)(r * 16 + dd) * 128)
                               : ((r == 8) ? (Wq + (size_t)dd * 128)
                                           : (Wk + (size_t)dd * 128));
    f32x4 v = *(const f32x4*)(row + m * 16 + g * 4);
    *(i32x4*)(wl + (size_t)wid * 16) = packhl(v[0], v[1], v[2], v[3]);
  }
  asm volatile("s_waitcnt vmcnt(0)" ::: "memory");
  __syncthreads();

  const int l = tid & 63, w = tid >> 6;
  const int p = l & 15, g = l >> 4;
  const int P = Pg * 4 + w;       // global 16-px col-tile
  const int pxl = w * 16 + p;     // px within block tile

  // biases
  float bvv[8];
#pragma unroll
  for (int r = 0; r < 8; r++) bvv[r] = bv[r * 16 + p];
  float bq4[4], bk4[4];
#pragma unroll
  for (int i = 0; i < 4; i++) {
    bq4[i] = bq[4 * g + i];
    bk4[i] = bk[4 * g + i];
  }

  const f32x4 zero4 = {0.f, 0.f, 0.f, 0.f};
  f32x4 acc[10];
#pragma unroll
  for (int r = 0; r < 10; r++) acc[r] = zero4;

#pragma unroll
  for (int m = 0; m < 8; m++) {
    // build x A/B-fragment: c = 16m+4g+j, px = pxl  (exact hi/lo split)
    float x0 = xl[(16 * m + 4 * g + 0) * 64 + pxl];
    float x1 = xl[(16 * m + 4 * g + 1) * 64 + pxl];
    float x2 = xl[(16 * m + 4 * g + 2) * 64 + pxl];
    float x3 = xl[(16 * m + 4 * g + 3) * 64 + pxl];
    i32x4 xm = packhl(x0, x1, x2, x3);
    i32x4 xs = {xm[2], xm[3], xm[0], xm[1]};  // swapped for cross-terms
#pragma unroll
    for (int r = 0; r < 10; r++) {
      i32x4 wm = *(const i32x4*)(wl + (size_t)((r * 8 + m) * 64 + l) * 16);
      if (r < 8) {  // V: D[px][d]
        acc[r] = __builtin_amdgcn_mfma_f32_16x16x32_bf16(asbf(xm), asbf(wm),
                                                         acc[r], 0, 0, 0);
        acc[r] = __builtin_amdgcn_mfma_f32_16x16x32_bf16(asbf(xs), asbf(wm),
                                                         acc[r], 0, 0, 0);
      } else {  // Q/K: D[e][n]
        acc[r] = __builtin_amdgcn_mfma_f32_16x16x32_bf16(asbf(wm), asbf(xm),
                                                         acc[r], 0, 0, 0);
        acc[r] = __builtin_amdgcn_mfma_f32_16x16x32_bf16(asbf(wm), asbf(xs),
                                                         acc[r], 0, 0, 0);
      }
    }
  }

  // ---- epilogue: bias, split hi/lo, store ----
  const int t = P >> 2, kc = P & 3;
  char* vg_t = Vg + (size_t)b * 2097152 + (size_t)t * 32768;
#pragma unroll
  for (int r = 0; r < 8; r++) {
    float v0 = acc[r][0] + bvv[r], v1 = acc[r][1] + bvv[r];
    float v2 = acc[r][2] + bvv[r], v3 = acc[r][3] + bvv[r];
    int d = r * 16 + p;
    *(i32x4*)(vg_t + ((size_t)((kc * 4 + g) * 128 + d)) * 16) =
        packhl(v0, v1, v2, v3);
  }
  {
    float v0 = acc[8][0] + bq4[0], v1 = acc[8][1] + bq4[1];
    float v2 = acc[8][2] + bq4[2], v3 = acc[8][3] + bq4[3];
    *(i32x4*)(Qg + ((size_t)(b * 16384 + g * 4096 + P * 16 + p)) * 16) =
        packhl(v0, v1, v2, v3);
    v0 = acc[9][0] + bk4[0]; v1 = acc[9][1] + bk4[1];
    v2 = acc[9][2] + bk4[2]; v3 = acc[9][3] + bk4[3];
    *(i32x4*)(Kg + ((size_t)(b * 16384 + g * 4096 + P * 16 + p)) * 16) =
        packhl(v0, v1, v2, v3);
  }
}

// ---------------------------------------------------------------------------
// Flash. 256 blocks (1/CU) x 512 thr (8 waves = kc(4) x qh(2)), 64 q/block.
// Wave: S^T for its 16 keys x 32 q (once, no dup), softmax in regs, PV over
// full d=128. Depth-2 register prefetch; epilogue LDS-reduce over kc.
// ---------------------------------------------------------------------------
#define COMPUTE(KF, V0, V1, V2, V3, V4, V5, V6, V7)                            \
  {                                                                            \
    i32x4 k2 = {KF[2], KF[3], KF[0], KF[1]};                                   \
    __builtin_amdgcn_s_setprio(1);                                             \
    f32x4 s0 = __builtin_amdgcn_mfma_f32_16x16x32_bf16(asbf(KF), asbf(qf0),    \
                                                       zero4, 0, 0, 0);        \
    s0 = __builtin_amdgcn_mfma_f32_16x16x32_bf16(asbf(k2), asbf(qf0), s0, 0,   \
                                                 0, 0);                        \
    f32x4 s1 = __builtin_amdgcn_mfma_f32_16x16x32_bf16(asbf(KF), asbf(qf1),    \
                                                       zero4, 0, 0, 0);        \
    s1 = __builtin_amdgcn_mfma_f32_16x16x32_bf16(asbf(k2), asbf(qf1), s1, 0,   \
                                                 0, 0);                        \
    __builtin_amdgcn_s_setprio(0);                                             \
    bf16x8 a0, a1;                                                             \
    {                                                                          \
      float p0 = PEXP(s0[0]), p1 = PEXP(s0[1]), p2 = PEXP(s0[2]),              \
            p3 = PEXP(s0[3]);                                                  \
      lsum0 += (p0 + p1) + (p2 + p3);                                          \
      int h0 = cvtpk(p0, p1), h1 = cvtpk(p2, p3);                              \
      i32x4 A = {h0, h1, h0, h1};                                              \
      a0 = asbf(A);                                                            \
    }                                                                          \
    {                                                                          \
      float p0 = PEXP(s1[0]), p1 = PEXP(s1[1]), p2 = PEXP(s1[2]),              \
            p3 = PEXP(s1[3]);                                                  \
      lsum1 += (p0 + p1) + (p2 + p3);                                          \
      int h0 = cvtpk(p0, p1), h1 = cvtpk(p2, p3);                              \
      i32x4 A = {h0, h1, h0, h1};                                              \
      a1 = asbf(A);                                                            \
    }                                                                          \
    __builtin_amdgcn_s_setprio(1);                                             \
    acc0[0] = __builtin_amdgcn_mfma_f32_16x16x32_bf16(a0, asbf(V0), acc0[0], 0, 0, 0); \
    acc0[1] = __builtin_amdgcn_mfma_f32_16x16x32_bf16(a0, asbf(V1), acc0[1], 0, 0, 0); \
    acc0[2] = __builtin_amdgcn_mfma_f32_16x16x32_bf16(a0, asbf(V2), acc0[2], 0, 0, 0); \
    acc0[3] = __builtin_amdgcn_mfma_f32_16x16x32_bf16(a0, asbf(V3), acc0[3], 0, 0, 0); \
    acc0[4] = __builtin_amdgcn_mfma_f32_16x16x32_bf16(a0, asbf(V4), acc0[4], 0, 0, 0); \
    acc0[5] = __builtin_amdgcn_mfma_f32_16x16x32_bf16(a0, asbf(V5), acc0[5], 0, 0, 0); \
    acc0[6] = __builtin_amdgcn_mfma_f32_16x16x32_bf16(a0, asbf(V6), acc0[6], 0, 0, 0); \
    acc0[7] = __builtin_amdgcn_mfma_f32_16x16x32_bf16(a0, asbf(V7), acc0[7], 0, 0, 0); \
    acc1[0] = __builtin_amdgcn_mfma_f32_16x16x32_bf16(a1, asbf(V0), acc1[0], 0, 0, 0); \
    acc1[1] = __builtin_amdgcn_mfma_f32_16x16x32_bf16(a1, asbf(V1), acc1[1], 0, 0, 0); \
    acc1[2] = __builtin_amdgcn_mfma_f32_16x16x32_bf16(a1, asbf(V2), acc1[2], 0, 0, 0); \
    acc1[3] = __builtin_amdgcn_mfma_f32_16x16x32_bf16(a1, asbf(V3), acc1[3], 0, 0, 0); \
    acc1[4] = __builtin_amdgcn_mfma_f32_16x16x32_bf16(a1, asbf(V4), acc1[4], 0, 0, 0); \
    acc1[5] = __builtin_amdgcn_mfma_f32_16x16x32_bf16(a1, asbf(V5), acc1[5], 0, 0, 0); \
    acc1[6] = __builtin_amdgcn_mfma_f32_16x16x32_bf16(a1, asbf(V6), acc1[6], 0, 0, 0); \
    acc1[7] = __builtin_amdgcn_mfma_f32_16x16x32_bf16(a1, asbf(V7), acc1[7], 0, 0, 0); \
    __builtin_amdgcn_s_setprio(0);                                             \
  }

#define LOADSET(KF, V0, V1, V2, V3, V4, V5, V6, V7, tt)                        \
  {                                                                            \
    unsigned vo = voff + (unsigned)(tt)*32768u;                                \
    V0 = *(const i32x4*)(vg_b + vo);                                           \
    V1 = *(const i32x4*)(vg_b + vo + 256);                                     \
    V2 = *(const i32x4*)(vg_b + vo + 512);                                     \
    V3 = *(const i32x4*)(vg_b + vo + 768);                                     \
    V4 = *(const i32x4*)(vg_b + vo + 1024);                                    \
    V5 = *(const i32x4*)(vg_b + vo + 1280);                                    \
    V6 = *(const i32x4*)(vg_b + vo + 1536);                                    \
    V7 = *(const i32x4*)(vg_b + vo + 1792);                                    \
    KF = *(const i32x4*)(kg_b + koff + (unsigned)(tt)*1024u);                  \
  }

__global__ __launch_bounds__(512, 2) void flash_kernel(
    const char* __restrict__ Qg, const char* __restrict__ Kg,
    const char* __restrict__ Vg, const float* __restrict__ xg,
    const float* __restrict__ gammag, float* __restrict__ outg) {
  __shared__ float red_O[64 * 129];
  __shared__ float red_L[64];

  const int bid = blockIdx.x;
  const int xcd = bid & 7;
  const int b = xcd >> 1;                        // batch pinned to XCD pair
  const int nt = ((bid >> 3) << 1) | (xcd & 1);  // 0..63
  const int n0 = nt << 6;

  const int tid = threadIdx.x;
  const int l = tid & 63, w = tid >> 6;
  const int c = l & 15, g = l >> 4;
  const int kc = w & 3, qh = w >> 2;

  const char* kg_b = Kg + (size_t)b * 262144;
  const char* vg_b = Vg + (size_t)b * 2097152;
  const unsigned voff = (unsigned)(((kc * 4 + g) * 128 + c) * 16);
  const unsigned koff = (unsigned)((g * 4096 + kc * 16 + c) * 16);

  const i32x4 qf0 = *(const i32x4*)(
      Qg + ((size_t)(b * 16384 + g * 4096 + n0 + qh * 32 + c)) * 16);
  const i32x4 qf1 = *(const i32x4*)(
      Qg + ((size_t)(b * 16384 + g * 4096 + n0 + qh * 32 + 16 + c)) * 16);

  const f32x4 zero4 = {0.f, 0.f, 0.f, 0.f};
  f32x4 acc0[8], acc1[8];
#pragma unroll
  for (int dt = 0; dt < 8; dt++) {
    acc0[dt] = zero4;
    acc1[dt] = zero4;
  }
  float lsum0 = 0.f, lsum1 = 0.f;

  i32x4 ka, va0, va1, va2, va3, va4, va5, va6, va7;
  i32x4 kb, vb0, vb1, vb2, vb3, vb4, vb5, vb6, vb7;
  LOADSET(ka, va0, va1, va2, va3, va4, va5, va6, va7, 0);
  LOADSET(kb, vb0, vb1, vb2, vb3, vb4, vb5, vb6, vb7, 1);

  for (int t = 0; t < 64; t += 2) {
    COMPUTE(ka, va0, va1, va2, va3, va4, va5, va6, va7);
    {
      int t2 = (t + 2 < 64) ? t + 2 : 63;
      LOADSET(ka, va0, va1, va2, va3, va4, va5, va6, va7, t2);
    }
    COMPUTE(kb, vb0, vb1, vb2, vb3, vb4, vb5, vb6, vb7);
    {
      int t3 = (t + 3 < 64) ? t + 3 : 63;
      LOADSET(kb, vb0, vb1, vb2, vb3, vb4, vb5, vb6, vb7, t3);
    }
  }

  // ---- epilogue: reduce over kc waves via LDS, out = gamma*O/L + x ----
  for (int i = tid; i < 64 * 129; i += 512) red_O[i] = 0.f;
  if (tid < 64) red_L[tid] = 0.f;
  __syncthreads();

  {
    float s = lsum0;
    s += __shfl_xor(s, 16);
    s += __shfl_xor(s, 32);
    if (g == 0) atomicAdd(&red_L[qh * 32 + c], s);
    s = lsum1;
    s += __shfl_xor(s, 16);
    s += __shfl_xor(s, 32);
    if (g == 0) atomicAdd(&red_L[qh * 32 + 16 + c], s);
  }
#pragma unroll
  for (int dt = 0; dt < 8; dt++) {
#pragma unroll
    for (int i = 0; i < 4; i++) {
      atomicAdd(&red_O[(qh * 32 + 4 * g + i) * 129 + dt * 16 + c], acc0[dt][i]);
      atomicAdd(&red_O[(qh * 32 + 16 + 4 * g + i) * 129 + dt * 16 + c],
                acc1[dt][i]);
    }
  }
  __syncthreads();

  const float gam = gammag[0];
#pragma unroll
  for (int k = 0; k < 4; k++) {
    int id = tid + k * 512;
    int q4 = id & 15, d = id >> 4;
    int q0 = q4 * 4;
    size_t base = ((size_t)(b * 128 + d)) * 4096 + n0 + q0;
    f32x4 x4 = *(const f32x4*)(xg + base);
    f32x4 o;
#pragma unroll
    for (int j = 0; j < 4; j++)
      o[j] = gam * (red_O[(q0 + j) * 129 + d] / red_L[q0 + j]) + x4[j];
    *(f32x4*)(outg + base) = o;
  }
}

// ---------------------------------------------------------------------------
extern "C" void kernel_launch(void* const* d_in, const int* in_sizes, int n_in,
                              void* d_out, int out_size, void* d_ws, size_t ws_size,
                              hipStream_t stream) {
  (void)in_sizes; (void)n_in; (void)out_size; (void)ws_size;
  const float* x = (const float*)d_in[0];
  const float* Wq = (const float*)d_in[1];
  const float* bq = (const float*)d_in[2];
  const float* Wk = (const float*)d_in[3];
  const float* bk = (const float*)d_in[4];
  const float* Wv = (const float*)d_in[5];
  const float* bv = (const float*)d_in[6];
  const float* gamma = (const float*)d_in[7];
  float* out = (float*)d_out;

  // ws layout: Qg 1MB | Kg 1MB | Vg 8MB
  char* Qg = (char*)d_ws;
  char* Kg = Qg + (1 << 20);
  char* Vg = Kg + (1 << 20);

  proj_kernel<<<256, 256, 0, stream>>>(x, Wq, bq, Wk, bk, Wv, bv, Qg, Kg, Vg);
  flash_kernel<<<256, 512, 0, stream>>>(Qg, Kg, Vg, x, gamma, out);
}